// Round 2
// baseline (8927.486 us; speedup 1.0000x reference)
//
#include <hip/hip_runtime.h>
#include <math.h>

#define Bb 64
#define Tt 2048
#define Ii 256
#define Hh 512
#define Oo 256

using f32x4   = __attribute__((ext_vector_type(4))) float;
using bf16x8  = __attribute__((ext_vector_type(8))) short;
using u32x4   = __attribute__((ext_vector_type(4))) unsigned int;
using ushort8 = __attribute__((ext_vector_type(8))) unsigned short;

__device__ __forceinline__ unsigned short f2bf(float f) {
    union { float f; unsigned u; } v; v.f = f;
    unsigned r = v.u + 0x7fffu + ((v.u >> 16) & 1u);
    return (unsigned short)(r >> 16);
}
__device__ __forceinline__ float bf2f(unsigned short b) {
    union { unsigned u; float f; } v; v.u = ((unsigned)b) << 16;
    return v.f;
}
__device__ __forceinline__ float tanh_fast(float x) {
    float e = __expf(2.0f * x);
    return 1.0f - 2.0f / (e + 1.0f);
}
__device__ __forceinline__ void cvt16(unsigned short* dst, const float* s) {
    u32x4 a, b;
#pragma unroll
    for (int i = 0; i < 4; ++i)
        a[i] = (unsigned)f2bf(s[2*i]) | ((unsigned)f2bf(s[2*i+1]) << 16);
#pragma unroll
    for (int i = 0; i < 4; ++i)
        b[i] = (unsigned)f2bf(s[8+2*i]) | ((unsigned)f2bf(s[8+2*i+1]) << 16);
    *(u32x4*)dst = a;
    *(u32x4*)(dst + 8) = b;
}

// Load one MFMA A-fragment of W_hh (rows = j_out, k = j_in), bf16-converted.
__device__ __forceinline__ bf16x8 w_frag(const float* __restrict__ W,
                                         int wv, int l15, int lhi, int u, int kt) {
    const float* p = W + (size_t)(wv*128 + u*16 + l15) * Hh + kt*32 + lhi*8;
    float s[8];
    *(f32x4*)&s[0] = *(const f32x4*)p;
    *(f32x4*)&s[4] = *(const f32x4*)(p + 4);
    bf16x8 v;
#pragma unroll
    for (int i = 0; i < 8; ++i) v[i] = (short)f2bf(s[i]);
    return v;
}

// ---------------- Phase 1: xp = x@W_ih^T + b_ih + b_hh, stored in k_rnn's
// per-thread fragment layout, in-place region (t,g) of buf -------------------
__global__ __launch_bounds__(256) void k_xproj(
    const float* __restrict__ x, const float* __restrict__ W_ih,
    const float* __restrict__ b_ih, const float* __restrict__ b_hh,
    unsigned short* __restrict__ buf)
{
    __shared__ __align__(16) unsigned short Asm[128][40];
    __shared__ __align__(16) unsigned short Bsm[128][40];
    __shared__ float bias_s[128];

    const int tid = threadIdx.x;
    const int lane = tid & 63, wv = tid >> 6;
    const int l15 = lane & 15, lhi = lane >> 4;
    const int r0 = blockIdx.x * 128, c0 = blockIdx.y * 128;

    if (tid < 128) { int c = c0 + tid; bias_s[tid] = b_ih[c] + b_hh[c]; }

    const int srow = tid >> 1, sks = (tid & 1) * 16;
    const int Rr = r0 + srow;
    const float* asrc = x + ((size_t)(Rr & 63) * Tt + (Rr >> 6)) * Ii + sks;
    const float* bsrc = W_ih + (size_t)(c0 + srow) * Ii + sks;

    const int m0 = (wv >> 1) * 64, n0 = (wv & 1) * 64;

    f32x4 acc[4][4];
#pragma unroll
    for (int i = 0; i < 4; ++i)
#pragma unroll
        for (int j = 0; j < 4; ++j) acc[i][j] = (f32x4){0.f,0.f,0.f,0.f};

    for (int kk = 0; kk < Ii/32; ++kk) {
        __syncthreads();
        {
            float s[16];
#pragma unroll
            for (int q = 0; q < 4; ++q) *(f32x4*)&s[q*4] = *(const f32x4*)(asrc + kk*32 + q*4);
            cvt16(&Asm[srow][sks], s);
#pragma unroll
            for (int q = 0; q < 4; ++q) *(f32x4*)&s[q*4] = *(const f32x4*)(bsrc + kk*32 + q*4);
            cvt16(&Bsm[srow][sks], s);
        }
        __syncthreads();
        bf16x8 af[4], bfr[4];
#pragma unroll
        for (int mi = 0; mi < 4; ++mi) af[mi]  = *(const bf16x8*)&Asm[m0 + mi*16 + l15][lhi*8];
#pragma unroll
        for (int ni = 0; ni < 4; ++ni) bfr[ni] = *(const bf16x8*)&Bsm[n0 + ni*16 + l15][lhi*8];
#pragma unroll
        for (int mi = 0; mi < 4; ++mi)
#pragma unroll
            for (int ni = 0; ni < 4; ++ni)
                acc[mi][ni] = __builtin_amdgcn_mfma_f32_16x16x32_bf16(af[mi], bfr[ni], acc[mi][ni], 0, 0, 0);
    }
    // Epilogue: write xp element (R=t*64+b, c) at k_rnn's fragment address.
#pragma unroll
    for (int mi = 0; mi < 4; ++mi)
#pragma unroll
        for (int ni = 0; ni < 4; ++ni) {
            int n = n0 + ni*16 + l15;
            int c = c0 + n;
            float bias = bias_s[n];
            int w2 = c >> 7, u2 = (c >> 4) & 7, clhi = (c >> 2) & 3, cri = c & 3;
#pragma unroll
            for (int ri = 0; ri < 4; ++ri) {
                int m = m0 + mi*16 + lhi*4 + ri;
                int R = r0 + m;
                int tt2 = R >> 6, b = R & 63;
                int tid2 = w2*64 + clhi*16 + (b & 15);
                size_t addr = ((size_t)tt2*4 + (b >> 4)) * 8192
                            + (size_t)(u2 >> 1) * 2048 + (size_t)tid2 * 8
                            + (u2 & 1) * 4 + cri;
                buf[addr] = f2bf(acc[mi][ni][ri] + bias);
            }
        }
}

// ---------------- Phase 2: recurrence, one block per 16-row batch group ----
// 4 blocks x 256 threads (4 waves, 1/SIMD, 512-VGPR budget). W_hh slice per
// wave: 100 frags in regs + 28 frags in LDS. h exchanged via __syncthreads.
__global__ __launch_bounds__(256, 1) void k_rnn(
    const float* __restrict__ W_hh, unsigned short* buf)
{
    __shared__ __align__(16) char wl[114688];  // 4 waves x 28 frags x 1KB
    __shared__ __align__(16) char hs[16384];   // h [16 rows][512 cols] bf16, XOR-swz

    const int tid = threadIdx.x;
    const int lane = tid & 63, wv = tid >> 6;
    const int l15 = lane & 15, lhi = lane >> 4;
    const int g = blockIdx.x;

    // persistent W fragments (A-operand: rows = j_out = wv*128+u*16+l15)
    bf16x8 WR[8][12];
    bf16x8 WR12[4];
#pragma unroll
    for (int u = 0; u < 8; ++u)
#pragma unroll
        for (int kt = 0; kt < 12; ++kt)
            WR[u][kt] = w_frag(W_hh, wv, l15, lhi, u, kt);
#pragma unroll
    for (int u = 0; u < 4; ++u) WR12[u] = w_frag(W_hh, wv, l15, lhi, u, 12);

    char* wbase = wl + wv * 28672 + lane * 16;
#pragma unroll
    for (int kt = 13; kt < 16; ++kt)
#pragma unroll
        for (int u = 0; u < 8; ++u)
            *(bf16x8*)(wbase + ((kt-13)*8 + u) * 1024) = w_frag(W_hh, wv, l15, lhi, u, kt);
#pragma unroll
    for (int u = 4; u < 8; ++u)
        *(bf16x8*)(wbase + (20 + u) * 1024) = w_frag(W_hh, wv, l15, lhi, u, 12);

    __syncthreads();

    const int swz = (l15 & 7) << 4;

    for (int t = 0; t < Tt; ++t) {
        // xp in fragment layout: 4 coalesced 16B chunks per thread
        const char* xpp = (const char*)buf + ((size_t)t*4 + g) * 16384 + (size_t)tid * 16;
        ushort8 xpc[4];
#pragma unroll
        for (int q = 0; q < 4; ++q)
            xpc[q] = *(const ushort8*)(xpp + (size_t)q * 4096);

        f32x4 acc[8];
#pragma unroll
        for (int u = 0; u < 8; ++u) acc[u] = (f32x4){0.f, 0.f, 0.f, 0.f};

        if (t > 0) {
#pragma unroll
            for (int kt = 0; kt < 16; ++kt) {
                // B-frag: h^T -> lane n=l15 (batch), k = kt*32+lhi*8..+7
                int byt = (l15 << 10) + (kt << 6) + (lhi << 4);
                bf16x8 hf = *(const bf16x8*)(hs + (byt ^ swz));
#pragma unroll
                for (int u = 0; u < 8; ++u) {
                    bf16x8 a;
                    if (kt < 12)                a = WR[u][kt];
                    else if (kt == 12 && u < 4) a = WR12[u];
                    else if (kt == 12)          a = *(const bf16x8*)(wbase + (20 + u) * 1024);
                    else                        a = *(const bf16x8*)(wbase + ((kt-13)*8 + u) * 1024);
                    acc[u] = __builtin_amdgcn_mfma_f32_16x16x32_bf16(a, hf, acc[u], 0, 0, 0);
                }
            }
        }
        __syncthreads();  // all reads of hs done before overwrite

        // epilogue: h = tanh(acc + xp); lane holds 4 consecutive j at batch=l15
        unsigned short* orow = buf + ((size_t)t*64 + g*16 + l15) * Hh + wv*128 + lhi*4;
#pragma unroll
        for (int u = 0; u < 8; ++u) {
            unsigned pk0, pk1;
            {
                float z0 = acc[u][0] + bf2f(xpc[u>>1][(u&1)*4 + 0]);
                float z1 = acc[u][1] + bf2f(xpc[u>>1][(u&1)*4 + 1]);
                pk0 = (unsigned)f2bf(tanh_fast(z0)) | ((unsigned)f2bf(tanh_fast(z1)) << 16);
            }
            {
                float z2 = acc[u][2] + bf2f(xpc[u>>1][(u&1)*4 + 2]);
                float z3 = acc[u][3] + bf2f(xpc[u>>1][(u&1)*4 + 3]);
                pk1 = (unsigned)f2bf(tanh_fast(z2)) | ((unsigned)f2bf(tanh_fast(z3)) << 16);
            }
            int byt = (l15 << 10) + (wv*128 + u*16 + lhi*4) * 2;
            *(uint2*)(hs + (byt ^ swz)) = make_uint2(pk0, pk1);
            *(uint2*)(orow + u*16) = make_uint2(pk0, pk1);
        }
        __syncthreads();  // hs complete before next step's reads
    }
}

// ---------------- Phase 3: out[b*T+t][o] = outs[t,b,:]·W_fc[o,:] + b_fc -----
__global__ __launch_bounds__(256) void k_fc(
    const unsigned short* __restrict__ buf, const float* __restrict__ W_fc,
    const float* __restrict__ b_fc, float* __restrict__ out)
{
    __shared__ __align__(16) unsigned short Asm[128][40];
    __shared__ __align__(16) unsigned short Bsm[128][40];
    __shared__ float bias_s[128];

    const int tid = threadIdx.x;
    const int lane = tid & 63, wv = tid >> 6;
    const int l15 = lane & 15, lhi = lane >> 4;
    const int r0 = blockIdx.x * 128, c0 = blockIdx.y * 128;

    if (tid < 128) bias_s[tid] = b_fc[c0 + tid];

    const int srow = tid >> 1, sks = (tid & 1) * 16;
    const unsigned short* asrc = buf + (size_t)(r0 + srow) * Hh + sks;
    const float* bsrc = W_fc + (size_t)(c0 + srow) * Hh + sks;

    const int m0 = (wv >> 1) * 64, n0 = (wv & 1) * 64;

    f32x4 acc[4][4];
#pragma unroll
    for (int i = 0; i < 4; ++i)
#pragma unroll
        for (int j = 0; j < 4; ++j) acc[i][j] = (f32x4){0.f,0.f,0.f,0.f};

    for (int kk = 0; kk < Hh/32; ++kk) {
        __syncthreads();
        {
            const unsigned short* pa = asrc + kk*32;
            *(u32x4*)&Asm[srow][sks]     = *(const u32x4*)pa;
            *(u32x4*)&Asm[srow][sks + 8] = *(const u32x4*)(pa + 8);
            float s[16];
#pragma unroll
            for (int q = 0; q < 4; ++q) *(f32x4*)&s[q*4] = *(const f32x4*)(bsrc + kk*32 + q*4);
            cvt16(&Bsm[srow][sks], s);
        }
        __syncthreads();
        bf16x8 af[4], bfr[4];
#pragma unroll
        for (int mi = 0; mi < 4; ++mi) af[mi]  = *(const bf16x8*)&Asm[m0 + mi*16 + l15][lhi*8];
#pragma unroll
        for (int ni = 0; ni < 4; ++ni) bfr[ni] = *(const bf16x8*)&Bsm[n0 + ni*16 + l15][lhi*8];
#pragma unroll
        for (int mi = 0; mi < 4; ++mi)
#pragma unroll
            for (int ni = 0; ni < 4; ++ni)
                acc[mi][ni] = __builtin_amdgcn_mfma_f32_16x16x32_bf16(af[mi], bfr[ni], acc[mi][ni], 0, 0, 0);
    }
#pragma unroll
    for (int mi = 0; mi < 4; ++mi)
#pragma unroll
        for (int ni = 0; ni < 4; ++ni) {
            int n = n0 + ni*16 + l15;
            float bias = bias_s[n];
#pragma unroll
            for (int ri = 0; ri < 4; ++ri) {
                int m = m0 + mi*16 + lhi*4 + ri;
                int R = r0 + m;                         // buf row = t*64+b
                int bb = R & 63, tt = R >> 6;
                out[((size_t)bb * Tt + tt) * Oo + (c0 + n)] = acc[mi][ni][ri] + bias;
            }
        }
}

// ---------------- Phase 4: hidden = h_{T-1} --------------------------------
__global__ void k_hid(const unsigned short* __restrict__ buf, float* __restrict__ hid) {
    int i = blockIdx.x * blockDim.x + threadIdx.x;
    if (i < Bb * Hh) {
        int b = i >> 9, j = i & 511;
        hid[i] = bf2f(buf[((size_t)(Tt - 1) * Bb + b) * Hh + j]);
    }
}

extern "C" void kernel_launch(void* const* d_in, const int* in_sizes, int n_in,
                              void* d_out, int out_size, void* d_ws, size_t ws_size,
                              hipStream_t stream) {
    (void)in_sizes; (void)n_in; (void)out_size; (void)ws_size;
    const float* x    = (const float*)d_in[0];
    const float* W_ih = (const float*)d_in[1];
    const float* W_hh = (const float*)d_in[2];
    const float* b_ih = (const float*)d_in[3];
    const float* b_hh = (const float*)d_in[4];
    const float* W_fc = (const float*)d_in[5];
    const float* b_fc = (const float*)d_in[6];
    float* out = (float*)d_out;

    unsigned short* buf = (unsigned short*)d_ws;  // [T*B][H] bf16: xp(frag) -> h (in place)

    k_xproj<<<dim3(1024, 4),  dim3(256), 0, stream>>>(x, W_ih, b_ih, b_hh, buf);
    k_rnn  <<<dim3(4),        dim3(256), 0, stream>>>(W_hh, buf);
    k_fc   <<<dim3(1024, 2),  dim3(256), 0, stream>>>(buf, W_fc, b_fc, out);
    k_hid  <<<dim3(64),       dim3(512), 0, stream>>>(buf, out + (size_t)Bb * Tt * Oo);
}

// Round 3
// 6673.891 us; speedup vs baseline: 1.3377x; 1.3377x over previous
//
#include <hip/hip_runtime.h>
#include <math.h>

#define Bb 64
#define Tt 2048
#define Ii 256
#define Hh 512
#define Oo 256

using f32x4   = __attribute__((ext_vector_type(4))) float;
using bf16x8  = __attribute__((ext_vector_type(8))) short;
using u32x4   = __attribute__((ext_vector_type(4))) unsigned int;

__device__ __forceinline__ unsigned short f2bf(float f) {
    union { float f; unsigned u; } v; v.f = f;
    unsigned r = v.u + 0x7fffu + ((v.u >> 16) & 1u);
    return (unsigned short)(r >> 16);
}
__device__ __forceinline__ float bf2f(unsigned short b) {
    union { unsigned u; float f; } v; v.u = ((unsigned)b) << 16;
    return v.f;
}
__device__ __forceinline__ float tanh_fast(float x) {
    float e = __expf(x + x);                       // v_exp path
    return 1.0f - 2.0f * __builtin_amdgcn_rcpf(e + 1.0f);
}
__device__ __forceinline__ unsigned cvt_pk(float lo, float hi) {
    unsigned r;
    asm volatile("v_cvt_pk_bf16_f32 %0, %1, %2" : "=v"(r) : "v"(lo), "v"(hi));
    return r;
}
__device__ __forceinline__ void cvt16(unsigned short* dst, const float* s) {
    u32x4 a, b;
#pragma unroll
    for (int i = 0; i < 4; ++i)
        a[i] = (unsigned)f2bf(s[2*i]) | ((unsigned)f2bf(s[2*i+1]) << 16);
#pragma unroll
    for (int i = 0; i < 4; ++i)
        b[i] = (unsigned)f2bf(s[8+2*i]) | ((unsigned)f2bf(s[8+2*i+1]) << 16);
    *(u32x4*)dst = a;
    *(u32x4*)(dst + 8) = b;
}

// One MFMA A-fragment of W_hh (row = output col j, k = input col), bf16.
__device__ __forceinline__ bf16x8 w_frag(const float* __restrict__ W,
                                         int row, int kt, int lhi) {
    const float* p = W + (size_t)row * Hh + kt*32 + lhi*8;
    float s[8];
    *(f32x4*)&s[0] = *(const f32x4*)p;
    *(f32x4*)&s[4] = *(const f32x4*)(p + 4);
    bf16x8 v;
#pragma unroll
    for (int i = 0; i < 8; ++i) v[i] = (short)f2bf(s[i]);
    return v;
}

// ---------------- Phase 1: xp = x@W_ih^T + b_ih + b_hh, stored in k_rnn's
// per-thread (512-thread) fragment layout, in-place region (t,g) of buf -----
__global__ __launch_bounds__(256) void k_xproj(
    const float* __restrict__ x, const float* __restrict__ W_ih,
    const float* __restrict__ b_ih, const float* __restrict__ b_hh,
    unsigned short* __restrict__ buf)
{
    __shared__ __align__(16) unsigned short Asm[128][40];
    __shared__ __align__(16) unsigned short Bsm[128][40];
    __shared__ float bias_s[128];

    const int tid = threadIdx.x;
    const int lane = tid & 63, wv = tid >> 6;
    const int l15 = lane & 15, lhi = lane >> 4;
    const int r0 = blockIdx.x * 128, c0 = blockIdx.y * 128;

    if (tid < 128) { int c = c0 + tid; bias_s[tid] = b_ih[c] + b_hh[c]; }

    const int srow = tid >> 1, sks = (tid & 1) * 16;
    const int Rr = r0 + srow;
    const float* asrc = x + ((size_t)(Rr & 63) * Tt + (Rr >> 6)) * Ii + sks;
    const float* bsrc = W_ih + (size_t)(c0 + srow) * Ii + sks;

    const int m0 = (wv >> 1) * 64, n0 = (wv & 1) * 64;

    f32x4 acc[4][4];
#pragma unroll
    for (int i = 0; i < 4; ++i)
#pragma unroll
        for (int j = 0; j < 4; ++j) acc[i][j] = (f32x4){0.f,0.f,0.f,0.f};

    for (int kk = 0; kk < Ii/32; ++kk) {
        __syncthreads();
        {
            float s[16];
#pragma unroll
            for (int q = 0; q < 4; ++q) *(f32x4*)&s[q*4] = *(const f32x4*)(asrc + kk*32 + q*4);
            cvt16(&Asm[srow][sks], s);
#pragma unroll
            for (int q = 0; q < 4; ++q) *(f32x4*)&s[q*4] = *(const f32x4*)(bsrc + kk*32 + q*4);
            cvt16(&Bsm[srow][sks], s);
        }
        __syncthreads();
        bf16x8 af[4], bfr[4];
#pragma unroll
        for (int mi = 0; mi < 4; ++mi) af[mi]  = *(const bf16x8*)&Asm[m0 + mi*16 + l15][lhi*8];
#pragma unroll
        for (int ni = 0; ni < 4; ++ni) bfr[ni] = *(const bf16x8*)&Bsm[n0 + ni*16 + l15][lhi*8];
#pragma unroll
        for (int mi = 0; mi < 4; ++mi)
#pragma unroll
            for (int ni = 0; ni < 4; ++ni)
                acc[mi][ni] = __builtin_amdgcn_mfma_f32_16x16x32_bf16(af[mi], bfr[ni], acc[mi][ni], 0, 0, 0);
    }
    // Epilogue: element (R=t*64+b, c) -> k_rnn fragment address.
    // k_rnn thread tid2 = wv2*64 + lhi2*16 + (b&15) reads ushort
    //   (t*4 + b>>4)*8192 + tid2*16 + u2*4 + ri2,
    // where wv2=c>>6, u2=(c>>4)&3, lhi2=(c>>2)&3, ri2=c&3.
#pragma unroll
    for (int mi = 0; mi < 4; ++mi)
#pragma unroll
        for (int ni = 0; ni < 4; ++ni) {
            int n = n0 + ni*16 + l15;
            int c = c0 + n;
            float bias = bias_s[n];
            int wv2 = c >> 6, u2 = (c >> 4) & 3, lhi2 = (c >> 2) & 3, ri2 = c & 3;
#pragma unroll
            for (int ri = 0; ri < 4; ++ri) {
                int m = m0 + mi*16 + lhi*4 + ri;
                int R = r0 + m;
                int tt2 = R >> 6, b = R & 63;
                int tid2 = wv2*64 + lhi2*16 + (b & 15);
                size_t addr = ((size_t)tt2*4 + (b >> 4)) * 8192
                            + (size_t)tid2 * 16 + u2*4 + ri2;
                buf[addr] = f2bf(acc[mi][ni][ri] + bias);
            }
        }
}

// ---------------- Phase 2: recurrence, 4 blocks x 512 threads --------------
// 8 waves (2/SIMD, 256-VGPR budget). Per wave: 64 output cols, W-frags:
// 47 in regs + 17 in LDS. h exchanged via LDS + __syncthreads only.
__global__ __launch_bounds__(512, 2) void k_rnn(
    const float* __restrict__ W_hh, unsigned short* buf)
{
    __shared__ __align__(16) char wl[139264];  // 8 waves x 17 frags x 1KB
    __shared__ __align__(16) char hs[16384];   // h [16 batch][512 j] bf16, XOR-swz

    const int tid = threadIdx.x;
    const int lane = tid & 63, wv = tid >> 6;
    const int l15 = lane & 15, lhi = lane >> 4;
    const int g = blockIdx.x;
    const int swz = (l15 & 7) << 4;

    // ---- persistent W fragments: wave wv owns j in [wv*64, wv*64+64)
    bf16x8 WR[47];   // kt<11: WR[kt*4+u]; kt==11,u<3: WR[44+u]
#pragma unroll
    for (int kt = 0; kt < 11; ++kt)
#pragma unroll
        for (int u = 0; u < 4; ++u)
            WR[kt*4 + u] = w_frag(W_hh, wv*64 + u*16 + l15, kt, lhi);
#pragma unroll
    for (int u = 0; u < 3; ++u)
        WR[44 + u] = w_frag(W_hh, wv*64 + u*16 + l15, 11, lhi);

    char* wbase = wl + wv * 17408 + lane * 16;
    *(bf16x8*)(wbase) = w_frag(W_hh, wv*64 + 48 + l15, 11, lhi);   // (kt11,u3)
#pragma unroll
    for (int kt = 12; kt < 16; ++kt)
#pragma unroll
        for (int u = 0; u < 4; ++u)
            *(bf16x8*)(wbase + (size_t)(1 + (kt-12)*4 + u) * 1024)
                = w_frag(W_hh, wv*64 + u*16 + l15, kt, lhi);
    __syncthreads();

#define PREF(A0, A1, TP_) do { \
    const u32x4* pp = (const u32x4*)((const char*)buf \
        + ((size_t)(TP_)*4 + g) * 16384 + (size_t)tid * 32); \
    A0 = pp[0]; A1 = pp[1]; \
  } while (0)

#define EPI(T_, X0, X1) do { \
    unsigned short* orow = buf + ((size_t)(T_)*64 + g*16 + l15) * Hh \
                         + (wv << 6) + (lhi << 2); \
    _Pragma("unroll") \
    for (int u = 0; u < 4; ++u) { \
        const u32x4 xv = (u < 2) ? X0 : X1; \
        float z[4]; \
        _Pragma("unroll") \
        for (int r = 0; r < 4; ++r) { \
            unsigned w = xv[(u & 1) * 2 + (r >> 1)]; \
            float xf = __uint_as_float((r & 1) ? (w & 0xffff0000u) : (w << 16)); \
            z[r] = acc[u][r] + xf; \
        } \
        uint2 pk; \
        pk.x = cvt_pk(tanh_fast(z[0]), tanh_fast(z[1])); \
        pk.y = cvt_pk(tanh_fast(z[2]), tanh_fast(z[3])); \
        int byt = (l15 << 10) + (wv << 7) + (u << 5) + (lhi << 3); \
        *(uint2*)(hs + (byt ^ swz)) = pk; \
        *(uint2*)(orow + (u << 4)) = pk; \
    } \
  } while (0)

#define STEP(T_, XU0, XU1, XP0, XP1, TP_) do { \
    PREF(XP0, XP1, TP_); \
    f32x4 acc[4]; \
    acc[0] = acc[1] = acc[2] = acc[3] = (f32x4){0.f, 0.f, 0.f, 0.f}; \
    __builtin_amdgcn_s_setprio(1); \
    _Pragma("unroll") \
    for (int kt = 0; kt < 16; ++kt) { \
        int byt = (l15 << 10) + (kt << 6) + (lhi << 4); \
        bf16x8 hf = *(const bf16x8*)(hs + (byt ^ swz)); \
        _Pragma("unroll") \
        for (int u = 0; u < 4; ++u) { \
            bf16x8 a; \
            if (kt < 11)                 a = WR[kt*4 + u]; \
            else if (kt == 11 && u < 3)  a = WR[44 + u]; \
            else if (kt == 11)           a = *(const bf16x8*)(wbase); \
            else a = *(const bf16x8*)(wbase + (size_t)(1 + (kt-12)*4 + u) * 1024); \
            acc[u] = __builtin_amdgcn_mfma_f32_16x16x32_bf16(a, hf, acc[u], 0, 0, 0); \
        } \
    } \
    __builtin_amdgcn_s_setprio(0); \
    asm volatile("" :: "v"(XU0[0]), "v"(XU1[0]));  /* vmcnt wait on consumed xp */ \
    __syncthreads();   /* hs reads + xp loads done -> safe to overwrite */ \
    EPI(T_, XU0, XU1); \
    __syncthreads();   /* h_t in hs before next step reads */ \
  } while (0)

    u32x4 xa0, xa1, xb0, xb1;
    PREF(xa0, xa1, 0);
    PREF(xb0, xb1, 1);

    {   // t = 0: h0 = tanh(xp0)
        f32x4 acc[4];
        acc[0] = acc[1] = acc[2] = acc[3] = (f32x4){0.f, 0.f, 0.f, 0.f};
        asm volatile("" :: "v"(xa0[0]), "v"(xa1[0]));
        __syncthreads();   // all xp(0) loads complete before any h(0) store
        EPI(0, xa0, xa1);
        __syncthreads();
    }

#pragma unroll 1
    for (int t = 1; t < Tt - 1; t += 2) {
        STEP(t,     xb0, xb1, xa0, xa1, t + 1);
        STEP(t + 1, xa0, xa1, xb0, xb1, (t + 2 < Tt ? t + 2 : Tt - 1));
    }
    STEP(Tt - 1, xb0, xb1, xa0, xa1, Tt - 1);   // final (dummy prefetch)

#undef PREF
#undef EPI
#undef STEP
}

// ---------------- Phase 3: out[b*T+t][o] = outs[t,b,:]·W_fc[o,:] + b_fc -----
__global__ __launch_bounds__(256) void k_fc(
    const unsigned short* __restrict__ buf, const float* __restrict__ W_fc,
    const float* __restrict__ b_fc, float* __restrict__ out)
{
    __shared__ __align__(16) unsigned short Asm[128][40];
    __shared__ __align__(16) unsigned short Bsm[128][40];
    __shared__ float bias_s[128];

    const int tid = threadIdx.x;
    const int lane = tid & 63, wv = tid >> 6;
    const int l15 = lane & 15, lhi = lane >> 4;
    const int r0 = blockIdx.x * 128, c0 = blockIdx.y * 128;

    if (tid < 128) bias_s[tid] = b_fc[c0 + tid];

    const int srow = tid >> 1, sks = (tid & 1) * 16;
    const unsigned short* asrc = buf + (size_t)(r0 + srow) * Hh + sks;
    const float* bsrc = W_fc + (size_t)(c0 + srow) * Hh + sks;

    const int m0 = (wv >> 1) * 64, n0 = (wv & 1) * 64;

    f32x4 acc[4][4];
#pragma unroll
    for (int i = 0; i < 4; ++i)
#pragma unroll
        for (int j = 0; j < 4; ++j) acc[i][j] = (f32x4){0.f,0.f,0.f,0.f};

    for (int kk = 0; kk < Hh/32; ++kk) {
        __syncthreads();
        {
            const unsigned short* pa = asrc + kk*32;
            *(u32x4*)&Asm[srow][sks]     = *(const u32x4*)pa;
            *(u32x4*)&Asm[srow][sks + 8] = *(const u32x4*)(pa + 8);
            float s[16];
#pragma unroll
            for (int q = 0; q < 4; ++q) *(f32x4*)&s[q*4] = *(const f32x4*)(bsrc + kk*32 + q*4);
            cvt16(&Bsm[srow][sks], s);
        }
        __syncthreads();
        bf16x8 af[4], bfr[4];
#pragma unroll
        for (int mi = 0; mi < 4; ++mi) af[mi]  = *(const bf16x8*)&Asm[m0 + mi*16 + l15][lhi*8];
#pragma unroll
        for (int ni = 0; ni < 4; ++ni) bfr[ni] = *(const bf16x8*)&Bsm[n0 + ni*16 + l15][lhi*8];
#pragma unroll
        for (int mi = 0; mi < 4; ++mi)
#pragma unroll
            for (int ni = 0; ni < 4; ++ni)
                acc[mi][ni] = __builtin_amdgcn_mfma_f32_16x16x32_bf16(af[mi], bfr[ni], acc[mi][ni], 0, 0, 0);
    }
#pragma unroll
    for (int mi = 0; mi < 4; ++mi)
#pragma unroll
        for (int ni = 0; ni < 4; ++ni) {
            int n = n0 + ni*16 + l15;
            float bias = bias_s[n];
#pragma unroll
            for (int ri = 0; ri < 4; ++ri) {
                int m = m0 + mi*16 + lhi*4 + ri;
                int R = r0 + m;                         // buf row = t*64+b
                int bb = R & 63, tt = R >> 6;
                out[((size_t)bb * Tt + tt) * Oo + (c0 + n)] = acc[mi][ni][ri] + bias;
            }
        }
}

// ---------------- Phase 4: hidden = h_{T-1} --------------------------------
__global__ void k_hid(const unsigned short* __restrict__ buf, float* __restrict__ hid) {
    int i = blockIdx.x * blockDim.x + threadIdx.x;
    if (i < Bb * Hh) {
        int b = i >> 9, j = i & 511;
        hid[i] = bf2f(buf[((size_t)(Tt - 1) * Bb + b) * Hh + j]);
    }
}

extern "C" void kernel_launch(void* const* d_in, const int* in_sizes, int n_in,
                              void* d_out, int out_size, void* d_ws, size_t ws_size,
                              hipStream_t stream) {
    (void)in_sizes; (void)n_in; (void)out_size; (void)ws_size;
    const float* x    = (const float*)d_in[0];
    const float* W_ih = (const float*)d_in[1];
    const float* W_hh = (const float*)d_in[2];
    const float* b_ih = (const float*)d_in[3];
    const float* b_hh = (const float*)d_in[4];
    const float* W_fc = (const float*)d_in[5];
    const float* b_fc = (const float*)d_in[6];
    float* out = (float*)d_out;

    unsigned short* buf = (unsigned short*)d_ws;  // [T*B][H] bf16: xp(frag) -> h (in place)

    k_xproj<<<dim3(1024, 4),  dim3(256), 0, stream>>>(x, W_ih, b_ih, b_hh, buf);
    k_rnn  <<<dim3(4),        dim3(512), 0, stream>>>(W_hh, buf);
    k_fc   <<<dim3(1024, 2),  dim3(256), 0, stream>>>(buf, W_fc, b_fc, out);
    k_hid  <<<dim3(64),       dim3(512), 0, stream>>>(buf, out + (size_t)Bb * Tt * Oo);
}